// Round 1
// baseline (30261.557 us; speedup 1.0000x reference)
//
#include <hip/hip_runtime.h>

// BiLSTM tagger, MI355X. Round 5: latency attack on k_recurrent.
// Counters showed k_recurrent is pure latency-bound (VALUBusy 1.2%, HBM 0.14%,
// 1236 ns/step): the per-step cost is the agent-scope (LLC) h-exchange + 2
// barriers + LDS relays. New k_recurrent:
//   - barrier-free wave-dataflow: 64 waves, each owns 8 units; every lane
//     directly polls its 32-unit tagged-h chunk from global; 8-lane butterfly
//     reduce; no __syncthreads / LDS relay in the main loop.
//   - runtime-probed same-XCD fast path: blocks b%8 in {0,1} (heuristically one
//     XCD per direction). A bounded functional probe (plain-store -> sc0-load
//     ping, 2 rounds, agent-scope AND rendezvous) verifies that the direction's
//     8 blocks share an L2; if yes, h-exchange uses plain store + sc0 load
//     (~200cy L2 RT); else falls back to sc0+sc1 (LLC, = old semantics).
//     Probe failure can only cause fallback, never a hang.
//   - vmcnt-counted poll: per step issue [2 stores][16 poll loads][4 pg loads],
//     wait vmcnt(4) -> polls done, depth-2 pregate HBM prefetch stays in
//     flight. Retry iterations wait vmcnt(0).
//   - Whh slice (4 gate rows x 32 k = 128 floats) register-resident per lane.
//
// Workspace (d_ws) ~92.5 MB (unchanged layout):
//   [0)          preC      256 KB
//   [262144)     whhTc     256 KB
//   [524288)     embeds    12 MB   [8192][384]
//   [13107200)   pregates  64 MB   [2][8192][1024]
//   [80216064)   hout      16 MB   [8192][512]  ([hf|hb])
//   [96993280)   hbuf      8 KB    [2][2][256] u64 tagged h (tag=step+1)
// Probe/verdict scratch: last 256 B of d_out (overwritten by k_output later).

#define S_LEN 8192
#define LC    16
#define DW    256
#define DC    64
#define HC    128
#define H2    256
#define NG    1024   // 4*H2
#define NTAG  64
#define CV    128

typedef unsigned long long u64;
typedef u64 u64x2 __attribute__((ext_vector_type(2)));

__device__ __forceinline__ float sigmoid_f(float x){
  return __frcp_rn(1.0f + __expf(-x));
}
__device__ __forceinline__ float tanh_f(float x){
  float a = fabsf(x);
  float t = 1.0f - 2.0f * __frcp_rn(__expf(2.0f*a) + 1.0f);
  return copysignf(t, x);
}

// ---------------------------------------------------------------- k_prep
__global__ __launch_bounds__(512) void k_prep(
    const float* __restrict__ char_emb, const float* __restrict__ char_Wih,
    const float* __restrict__ char_Whh, const float* __restrict__ char_b,
    float* __restrict__ preC, float* __restrict__ whhTc)
{
  int blk = blockIdx.x, tid = threadIdx.x;
  __shared__ float esh[DC];
  if (blk < CV){
    if (tid < DC) esh[tid] = char_emb[blk*DC + tid];
    __syncthreads();
    const float* wr = char_Wih + (size_t)tid*DC;
    float acc = char_b[tid];
#pragma unroll
    for (int d=0; d<DC; d+=4){
      float4 wv = *(const float4*)&wr[d];
      acc += wv.x*esh[d] + wv.y*esh[d+1] + wv.z*esh[d+2] + wv.w*esh[d+3];
    }
    preC[(size_t)blk*512 + tid] = acc;
  } else {
    int k = blk - CV;
    whhTc[(size_t)k*512 + tid] = char_Whh[(size_t)tid*HC + k];
  }
}

// ---------------------------------------------------------------- k_char_lstm
__global__ __launch_bounds__(256) void k_char_lstm(
    const int* __restrict__ charsets, const int* __restrict__ lengths,
    const float* __restrict__ preC, const float* __restrict__ whhTc,
    float* __restrict__ embeds)
{
  int blk = blockIdx.x, tid = threadIdx.x;
  int s0 = blk*16;
  __shared__ float h_sh[16][132];
  __shared__ float gsh[512][17];
  __shared__ int   ch_sh[16];

  for (int i = tid; i < 16*132; i += 256) (&h_sh[0][0])[i] = 0.0f;

  int uw  = tid & 15;
  int ujg = tid >> 4;
  float c[8];
#pragma unroll
  for (int u=0; u<8; u++) c[u] = 0.0f;
  int lw = lengths[s0 + uw];

  int g0 = tid, g1 = tid + 256;
  __syncthreads();

  for (int t=0; t<LC; t++){
    if (tid < 16) ch_sh[tid] = charsets[(size_t)(s0+tid)*LC + t];
    __syncthreads();                                        // (A)

    float acc0[16], acc1[16];
#pragma unroll
    for (int w=0; w<16; w++){
      int ch = ch_sh[w];
      acc0[w] = preC[(size_t)ch*512 + g0];
      acc1[w] = preC[(size_t)ch*512 + g1];
    }
    for (int k4=0; k4<HC; k4+=4){
      float w00 = whhTc[(size_t)(k4+0)*512 + g0];
      float w01 = whhTc[(size_t)(k4+1)*512 + g0];
      float w02 = whhTc[(size_t)(k4+2)*512 + g0];
      float w03 = whhTc[(size_t)(k4+3)*512 + g0];
      float w10 = whhTc[(size_t)(k4+0)*512 + g1];
      float w11 = whhTc[(size_t)(k4+1)*512 + g1];
      float w12 = whhTc[(size_t)(k4+2)*512 + g1];
      float w13 = whhTc[(size_t)(k4+3)*512 + g1];
#pragma unroll
      for (int w=0; w<16; w++){
        float4 h4 = *(const float4*)&h_sh[w][k4];
        acc0[w] += w00*h4.x + w01*h4.y + w02*h4.z + w03*h4.w;
        acc1[w] += w10*h4.x + w11*h4.y + w12*h4.z + w13*h4.w;
      }
    }
#pragma unroll
    for (int w=0; w<16; w++){ gsh[g0][w] = acc0[w]; gsh[g1][w] = acc1[w]; }
    __syncthreads();                                        // (G)

    float hnew[8];
#pragma unroll
    for (int u=0; u<8; u++){
      int j = ujg*8 + u;
      float gi = sigmoid_f(gsh[j][uw]);
      float gf = sigmoid_f(gsh[HC + j][uw]);
      float gg = tanh_f   (gsh[2*HC + j][uw]);
      float go = sigmoid_f(gsh[3*HC + j][uw]);
      c[u] = gf*c[u] + gi*gg;
      hnew[u] = go * tanh_f(c[u]);
    }
#pragma unroll
    for (int u=0; u<8; u+=4)
      *(float4*)&h_sh[uw][ujg*8 + u] = make_float4(hnew[u],hnew[u+1],hnew[u+2],hnew[u+3]);
    if (t == lw-1){
#pragma unroll
      for (int u=0; u<8; u+=4)
        *(float4*)&embeds[(size_t)(s0+uw)*384 + ujg*8 + u]
            = make_float4(hnew[u],hnew[u+1],hnew[u+2],hnew[u+3]);
    }
  }
}

// ---------------------------------------------------------------- k_gather
__global__ __launch_bounds__(256) void k_gather(
    const int* __restrict__ sentence, const float* __restrict__ word_emb,
    float* __restrict__ embeds)
{
  int blk = blockIdx.x, tid = threadIdx.x;
  int s = blk*8 + (tid >> 5);
  int lane = tid & 31;
  int idx = sentence[s];
  const float4* src = (const float4*)(word_emb + (size_t)idx*DW);
  float4* dst = (float4*)(embeds + (size_t)s*384 + 128);
  dst[lane]      = src[lane];
  dst[lane + 32] = src[lane + 32];
}

// ---------------------------------------------------------------- k_pregate
// Output layout: pregates[dir][t][n], n = gate-major (PyTorch i,f,g,o blocks of 256)
__global__ __launch_bounds__(256) void k_pregate(
    const float* __restrict__ embeds,
    const float* __restrict__ Wih_fw, const float* __restrict__ b_fw,
    const float* __restrict__ Wih_bw, const float* __restrict__ b_bw,
    float* __restrict__ pregates)
{
  int dir = blockIdx.z;
  const float* W    = dir ? Wih_bw : Wih_fw;
  const float* bias = dir ? b_bw   : b_fw;
  int t0 = blockIdx.x*64, n0 = blockIdx.y*64;
  __shared__ float a_sh[16][68];
  __shared__ float b_sh[16][68];
  int tid = threadIdx.x;
  int li = tid & 63, kq = tid >> 6;
  int ti = tid >> 4, tj = tid & 15;
  float acc[4][4];
#pragma unroll
  for (int ii=0; ii<4; ii++)
#pragma unroll
    for (int jj=0; jj<4; jj++) acc[ii][jj] = 0.0f;

  for (int k0=0; k0<384; k0+=16){
    float4 av = *(const float4*)&embeds[(size_t)(t0+li)*384 + k0 + kq*4];
    float4 bv = *(const float4*)&W     [(size_t)(n0+li)*384 + k0 + kq*4];
    __syncthreads();
    a_sh[kq*4+0][li]=av.x; a_sh[kq*4+1][li]=av.y; a_sh[kq*4+2][li]=av.z; a_sh[kq*4+3][li]=av.w;
    b_sh[kq*4+0][li]=bv.x; b_sh[kq*4+1][li]=bv.y; b_sh[kq*4+2][li]=bv.z; b_sh[kq*4+3][li]=bv.w;
    __syncthreads();
#pragma unroll
    for (int kk=0; kk<16; kk++){
      float4 a4 = *(const float4*)&a_sh[kk][ti*4];
      float4 b4 = *(const float4*)&b_sh[kk][tj*4];
      float aa[4] = {a4.x,a4.y,a4.z,a4.w};
      float bb[4] = {b4.x,b4.y,b4.z,b4.w};
#pragma unroll
      for (int ii=0; ii<4; ii++)
#pragma unroll
        for (int jj=0; jj<4; jj++) acc[ii][jj] += aa[ii]*bb[jj];
    }
  }
  float4 bias4 = *(const float4*)&bias[n0 + tj*4];
  float bb2[4] = {bias4.x,bias4.y,bias4.z,bias4.w};
#pragma unroll
  for (int ii=0; ii<4; ii++){
    float4 o = make_float4(acc[ii][0]+bb2[0], acc[ii][1]+bb2[1],
                           acc[ii][2]+bb2[2], acc[ii][3]+bb2[3]);
    *(float4*)&pregates[((size_t)dir*S_LEN + (t0+ti*4+ii))*NG + n0 + tj*4] = o;
  }
}

// ---------------------------------------------------------------- k_recurrent
// Communication primitives.
// FAST (same-XCD, probe-verified): plain store (write-through L1 -> shared L2),
//   sc0 load (L1 bypass, reads the shared L2).
// LLC  (always-correct fallback): sc0 sc1 both ways = device coherence point,
//   identical semantics to the previous agent-scope kernel.
__device__ __forceinline__ void st_u32_fast(unsigned* p, unsigned v){
  asm volatile("global_store_dword %0, %1, off" :: "v"(p), "v"(v) : "memory");
}
__device__ __forceinline__ unsigned ld_u32_fast(const unsigned* p){
  unsigned r;
  asm volatile("global_load_dword %0, %1, off sc0\n\t"
               "s_waitcnt vmcnt(0)"
               : "=v"(r) : "v"(p) : "memory");
  return r;
}
template<bool LLC>
__device__ __forceinline__ void st_h64(u64* p, u64 v){
  if constexpr (LLC)
    asm volatile("global_store_dwordx2 %0, %1, off sc0 sc1" :: "v"(p), "v"(v) : "memory");
  else
    asm volatile("global_store_dwordx2 %0, %1, off" :: "v"(p), "v"(v) : "memory");
}

// 16x dwordx4 = 32 tagged u64 (this lane's 32-unit h chunk), one address, imm offsets.
#define POLL16(BITS) \
  asm volatile( \
    "global_load_dwordx4 %0, %16, off " BITS "\n\t" \
    "global_load_dwordx4 %1, %16, off offset:16 " BITS "\n\t" \
    "global_load_dwordx4 %2, %16, off offset:32 " BITS "\n\t" \
    "global_load_dwordx4 %3, %16, off offset:48 " BITS "\n\t" \
    "global_load_dwordx4 %4, %16, off offset:64 " BITS "\n\t" \
    "global_load_dwordx4 %5, %16, off offset:80 " BITS "\n\t" \
    "global_load_dwordx4 %6, %16, off offset:96 " BITS "\n\t" \
    "global_load_dwordx4 %7, %16, off offset:112 " BITS "\n\t" \
    "global_load_dwordx4 %8, %16, off offset:128 " BITS "\n\t" \
    "global_load_dwordx4 %9, %16, off offset:144 " BITS "\n\t" \
    "global_load_dwordx4 %10, %16, off offset:160 " BITS "\n\t" \
    "global_load_dwordx4 %11, %16, off offset:176 " BITS "\n\t" \
    "global_load_dwordx4 %12, %16, off offset:192 " BITS "\n\t" \
    "global_load_dwordx4 %13, %16, off offset:208 " BITS "\n\t" \
    "global_load_dwordx4 %14, %16, off offset:224 " BITS "\n\t" \
    "global_load_dwordx4 %15, %16, off offset:240 " BITS \
    : "=&v"(r0),"=&v"(r1),"=&v"(r2),"=&v"(r3),"=&v"(r4),"=&v"(r5),"=&v"(r6),"=&v"(r7), \
      "=&v"(r8),"=&v"(r9),"=&v"(r10),"=&v"(r11),"=&v"(r12),"=&v"(r13),"=&v"(r14),"=&v"(r15) \
    : "v"(pp2) : "memory")

#define CHK(R) ((((unsigned)(R).x) ^ tg) | (((unsigned)(R).y) ^ tg))
#define CHKALL (CHK(r0)|CHK(r1)|CHK(r2)|CHK(r3)|CHK(r4)|CHK(r5)|CHK(r6)|CHK(r7)| \
                CHK(r8)|CHK(r9)|CHK(r10)|CHK(r11)|CHK(r12)|CHK(r13)|CHK(r14)|CHK(r15))
#define UNP(i, R) { h[2*(i)]   = __uint_as_float((unsigned)((R).x >> 32)); \
                    h[2*(i)+1] = __uint_as_float((unsigned)((R).y >> 32)); }

template<bool LLC>
__device__ __forceinline__ void recurrent_loop(
    int dir, int unit, int ke,
    const float* __restrict__ Whh,
    const float* __restrict__ pgb,
    u64* __restrict__ hb,
    float* __restrict__ hout)
{
  // Whh slice: 4 gate rows (i,f,g,o of this unit), k in [ke*32, ke*32+32).
  float w0[32], w1[32], w2[32], w3[32];
  {
    const float* bp = Whh + (size_t)unit*H2 + (size_t)ke*32;
#pragma unroll
    for (int j=0; j<8; j++){
      float4 v;
      v = *(const float4*)(bp + 0*65536 + j*4);
      w0[j*4]=v.x; w0[j*4+1]=v.y; w0[j*4+2]=v.z; w0[j*4+3]=v.w;
      v = *(const float4*)(bp + 1*65536 + j*4);
      w1[j*4]=v.x; w1[j*4+1]=v.y; w1[j*4+2]=v.z; w1[j*4+3]=v.w;
      v = *(const float4*)(bp + 2*65536 + j*4);
      w2[j*4]=v.x; w2[j*4+1]=v.y; w2[j*4+2]=v.z; w2[j*4+3]=v.w;
      v = *(const float4*)(bp + 3*65536 + j*4);
      w3[j*4]=v.x; w3[j*4+1]=v.y; w3[j*4+2]=v.z; w3[j*4+3]=v.w;
    }
  }
  float h[32];
#pragma unroll
  for (int k=0; k<32; k++) h[k] = 0.0f;
  float c = 0.0f;

  // pregate depth-2 pipeline (prologue loads via plain C; compiler waits)
  float pc0,pc1,pc2,pc3, pn0,pn1,pn2,pn3;
  {
    int t0 = dir ? (S_LEN-1) : 0;
    const float* pa = pgb + (size_t)t0*NG + unit;
    pc0 = pa[0]; pc1 = pa[256]; pc2 = pa[512]; pc3 = pa[768];
    int t1 = dir ? (S_LEN-2) : 1;
    const float* pb = pgb + (size_t)t1*NG + unit;
    pn0 = pb[0]; pn1 = pb[256]; pn2 = pb[512]; pn3 = pb[768];
  }

  for (int s=0; s<S_LEN; ++s){
    // gates = Whh_slice . h_chunk, reduced over the 8 ke-lanes, + pregate
    float a0=0.f, a1=0.f, a2=0.f, a3=0.f;
#pragma unroll
    for (int k=0; k<32; k++){
      a0 += w0[k]*h[k]; a1 += w1[k]*h[k]; a2 += w2[k]*h[k]; a3 += w3[k]*h[k];
    }
    a0 += __shfl_xor(a0,1); a1 += __shfl_xor(a1,1); a2 += __shfl_xor(a2,1); a3 += __shfl_xor(a3,1);
    a0 += __shfl_xor(a0,2); a1 += __shfl_xor(a1,2); a2 += __shfl_xor(a2,2); a3 += __shfl_xor(a3,2);
    a0 += __shfl_xor(a0,4); a1 += __shfl_xor(a1,4); a2 += __shfl_xor(a2,4); a3 += __shfl_xor(a3,4);
    a0 += pc0; a1 += pc1; a2 += pc2; a3 += pc3;   // pregate added ONCE, post-reduce

    float gi = sigmoid_f(a0), gf = sigmoid_f(a1), gg = tanh_f(a2), go = sigmoid_f(a3);
    c = gf*c + gi*gg;
    float hn = go * tanh_f(c);

    int t = dir ? (S_LEN-1-s) : s;
    u64* hslot = hb + (size_t)(s&1)*H2;
    if (ke == 0){
      u64 pack = ((u64)__float_as_uint(hn) << 32) | (u64)(unsigned)(s+1);
      st_h64<LLC>(hslot + unit, pack);
      float* hop = hout + (size_t)t*512 + (size_t)dir*H2 + unit;
      asm volatile("global_store_dword %0, %1, off" :: "v"(hop), "v"(hn) : "memory");
    }
    if (s+1 == S_LEN) break;

    // poll this lane's chunk of h(s) (tag s+1) + issue next pregate prefetch.
    // vmem issue order per step: [<=2 stores][16 polls][4 pg] -> vmcnt(4)
    // guarantees stores+polls complete while pg (HBM) stays in flight.
    const u64* pp2 = hslot + (size_t)ke*32;
    unsigned tg = (unsigned)(s+1);
    u64x2 r0,r1,r2,r3,r4,r5,r6,r7,r8,r9,r10,r11,r12,r13,r14,r15;
    if constexpr (LLC) { POLL16("sc0 sc1"); } else { POLL16("sc0"); }
    float q0,q1,q2,q3;
    {
      int t2r = (s+2 < S_LEN) ? (s+2) : s;     // clamp keeps vmem count uniform
      int t2  = dir ? (S_LEN-1-t2r) : t2r;
      const float* pa = pgb + (size_t)t2*NG + unit;
      asm volatile(
        "global_load_dword %0, %4, off\n\t"
        "global_load_dword %1, %4, off offset:1024\n\t"
        "global_load_dword %2, %4, off offset:2048\n\t"
        "global_load_dword %3, %4, off offset:3072"
        : "=&v"(q0),"=&v"(q1),"=&v"(q2),"=&v"(q3) : "v"(pa) : "memory");
    }
    asm volatile("s_waitcnt vmcnt(4)" ::: "memory");
    __builtin_amdgcn_sched_barrier(0);
    unsigned bad = CHKALL;
    while (bad){
      if constexpr (LLC) { POLL16("sc0 sc1"); } else { POLL16("sc0"); }
      asm volatile("s_waitcnt vmcnt(0)" ::: "memory");
      __builtin_amdgcn_sched_barrier(0);
      bad = CHKALL;
    }
    UNP(0,r0)  UNP(1,r1)  UNP(2,r2)  UNP(3,r3)
    UNP(4,r4)  UNP(5,r5)  UNP(6,r6)  UNP(7,r7)
    UNP(8,r8)  UNP(9,r9)  UNP(10,r10) UNP(11,r11)
    UNP(12,r12) UNP(13,r13) UNP(14,r14) UNP(15,r15)

    pc0 = pn0; pc1 = pn1; pc2 = pn2; pc3 = pn3;
    pn0 = q0;  pn1 = q1;  pn2 = q2;  pn3 = q3;
    // q* (issued this step) are guaranteed complete before use at step s+2:
    // step s+1's vmcnt(4)/vmcnt(0) retires everything older than its own pg.
  }
}

// 64 blocks x 256; active: (b&7)<2. dir=b&7, slot=b>>3. Wave (slot*4+wv) owns
// units [W*8, W*8+8); lane (ul,ke) holds 4 gate rows x 32-k Whh slice in VGPRs.
__global__ __launch_bounds__(256, 1) void k_recurrent(
    const float* __restrict__ Whh_fw, const float* __restrict__ Whh_bw,
    const float* __restrict__ pregates,
    u64* __restrict__ hbuf,
    float* __restrict__ hout,
    unsigned* __restrict__ scratch)
{
  int b = blockIdx.x;
  if ((b & 7) > 1) return;
  const int dir  = b & 7;          // 0 or 1
  const int slot = b >> 3;         // 0..7
  const int tid  = threadIdx.x;
  const int wv   = tid >> 6, lane = tid & 63;
  const int ul   = lane >> 3, ke = lane & 7;
  const int unit = (slot*4 + wv)*8 + ul;

  // ---- functional same-XCD probe (bounded; any failure -> LLC fallback) ----
  __shared__ int fast_sh;
  if (tid == 0){
    unsigned* probe = scratch;        // [16]
    unsigned* verd1 = scratch + 16;   // [16]
    unsigned* verd2 = scratch + 32;   // [16]
    // round 1: can I see my 7 peers' plain stores via sc0 loads?
    st_u32_fast(&probe[dir*8 + slot], 0xA5C70000u | (unsigned)slot);
    unsigned have = 0;
    for (int it = 0; it < 400 && have != 0xFFu; ++it)
      for (int i = 0; i < 8; ++i)
        if (!((have >> i) & 1u) &&
            ld_u32_fast(&probe[dir*8 + i]) == (0xA5C70000u | (unsigned)i))
          have |= 1u << i;
    unsigned ok = (have == 0xFFu) ? 1u : 0u;
    __hip_atomic_store(&verd1[dir*8 + slot], 0x5EED0000u | ok,
                       __ATOMIC_RELAXED, __HIP_MEMORY_SCOPE_AGENT);
    unsigned f1 = 1;
    for (int i = 0; i < 8; ++i){
      unsigned v;
      do v = __hip_atomic_load(&verd1[dir*8 + i], __ATOMIC_RELAXED, __HIP_MEMORY_SCOPE_AGENT);
      while ((v & 0xFFFF0000u) != 0x5EED0000u);
      f1 &= v & 1u;
    }
    // round 2: re-ping with new magic (defeats the evicted-dirty-line false
    // positive: a stale round-1 line in a foreign L2 cannot show round-2 magic).
    unsigned f2 = 0;
    if (f1){
      st_u32_fast(&probe[dir*8 + slot], 0x0DDB0000u | (unsigned)slot);
      have = 0;
      for (int it = 0; it < 400 && have != 0xFFu; ++it)
        for (int i = 0; i < 8; ++i)
          if (!((have >> i) & 1u) &&
              ld_u32_fast(&probe[dir*8 + i]) == (0x0DDB0000u | (unsigned)i))
            have |= 1u << i;
      ok = (have == 0xFFu) ? 1u : 0u;
      __hip_atomic_store(&verd2[dir*8 + slot], 0x7EED0000u | ok,
                         __ATOMIC_RELAXED, __HIP_MEMORY_SCOPE_AGENT);
      f2 = 1;
      for (int i = 0; i < 8; ++i){
        unsigned v;
        do v = __hip_atomic_load(&verd2[dir*8 + i], __ATOMIC_RELAXED, __HIP_MEMORY_SCOPE_AGENT);
        while ((v & 0xFFFF0000u) != 0x7EED0000u);
        f2 &= v & 1u;
      }
    }
    fast_sh = (int)(f1 & f2);
  }
  __syncthreads();
  const bool fast = (fast_sh != 0);

  const float* Whh = dir ? Whh_bw : Whh_fw;
  const float* pgb = pregates + (size_t)dir * S_LEN * NG;
  u64* hb = hbuf + (size_t)dir * 2 * H2;

  if (fast) recurrent_loop<false>(dir, unit, ke, Whh, pgb, hb, hout);
  else      recurrent_loop<true >(dir, unit, ke, Whh, pgb, hb, hout);
}

// ---------------------------------------------------------------- k_output
__global__ __launch_bounds__(256) void k_output(
    const float* __restrict__ hout, const float* __restrict__ outW,
    const float* __restrict__ outb, float* __restrict__ out)
{
  __shared__ float wT[128][66];
  __shared__ float hsh[32][132];
  __shared__ float lsh[32][66];
  __shared__ float msh[32][2];
  int t0 = blockIdx.x*32, tid = threadIdx.x;
  int n  = tid & 63, tg = tid >> 6;
  int sl = tid >> 3, kg = tid & 7;
  int wn = tid & 63, wk = tid >> 6;
  float acc[8];
#pragma unroll
  for (int u=0; u<8; u++) acc[u] = 0.0f;

  for (int kc=0; kc<4; kc++){
    int k0 = kc*128;
    float4 wreg[8];
#pragma unroll
    for (int e=0; e<8; e++) wreg[e] = *(const float4*)&outW[(size_t)wn*512 + k0 + wk*32 + e*4];
    float4 hreg[4];
#pragma unroll
    for (int e=0; e<4; e++) hreg[e] = *(const float4*)&hout[(size_t)(t0+sl)*512 + k0 + kg*16 + e*4];
    __syncthreads();
#pragma unroll
    for (int e=0; e<8; e++){
      int kk = wk*32 + e*4;
      wT[kk+0][wn]=wreg[e].x; wT[kk+1][wn]=wreg[e].y; wT[kk+2][wn]=wreg[e].z; wT[kk+3][wn]=wreg[e].w;
    }
#pragma unroll
    for (int e=0; e<4; e++) *(float4*)&hsh[sl][kg*16 + e*4] = hreg[e];
    __syncthreads();
#pragma unroll
    for (int kk4=0; kk4<128; kk4+=4){
      float w0 = wT[kk4+0][n], w1 = wT[kk4+1][n], w2 = wT[kk4+2][n], w3 = wT[kk4+3][n];
#pragma unroll
      for (int u=0; u<8; u++){
        float4 h4 = *(const float4*)&hsh[tg*8+u][kk4];
        acc[u] += w0*h4.x + w1*h4.y + w2*h4.z + w3*h4.w;
      }
    }
  }
  float bn = outb[n];
#pragma unroll
  for (int u=0; u<8; u++) lsh[tg*8+u][n] = acc[u] + bn;
  __syncthreads();
  if (tid < 32){
    float M = -3.4e38f;
    for (int j=0; j<NTAG; j++) M = fmaxf(M, lsh[tid][j]);
    float ssum = 0.0f;
    for (int j=0; j<NTAG; j++) ssum += expf(lsh[tid][j] - M);
    msh[tid][0] = M; msh[tid][1] = logf(ssum);
  }
  __syncthreads();
#pragma unroll
  for (int u=0; u<8; u++){
    int tt = tg*8+u;
    out[(size_t)(t0+tt)*NTAG + n] = lsh[tt][n] - msh[tt][0] - msh[tt][1];
  }
}

// ---------------------------------------------------------------- launch
extern "C" void kernel_launch(void* const* d_in, const int* in_sizes, int n_in,
                              void* d_out, int out_size, void* d_ws, size_t ws_size,
                              hipStream_t stream)
{
  (void)in_sizes; (void)n_in; (void)out_size; (void)ws_size;
  const int*   sentence = (const int*)d_in[0];
  const int*   charsets = (const int*)d_in[1];
  const int*   char_len = (const int*)d_in[2];
  const float* word_emb = (const float*)d_in[3];
  const float* char_emb = (const float*)d_in[4];
  const float* char_Wih = (const float*)d_in[5];
  const float* char_Whh = (const float*)d_in[6];
  const float* char_b   = (const float*)d_in[7];
  const float* fw_Wih   = (const float*)d_in[8];
  const float* fw_Whh   = (const float*)d_in[9];
  const float* fw_b     = (const float*)d_in[10];
  const float* bw_Wih   = (const float*)d_in[11];
  const float* bw_Whh   = (const float*)d_in[12];
  const float* bw_b     = (const float*)d_in[13];
  const float* out_W    = (const float*)d_in[14];
  const float* out_b    = (const float*)d_in[15];
  float* out = (float*)d_out;

  char* ws = (char*)d_ws;
  float* preC     = (float*)(ws);
  float* whhTc    = (float*)(ws + 262144);
  float* embeds   = (float*)(ws + 524288);
  float* pregates = (float*)(ws + 13107200);
  float* houtb    = (float*)(ws + 80216064);
  u64*   hbuf     = (u64*)(ws + 96993280);
  // probe/verdict scratch: last 256 B of d_out (k_output overwrites it later).
  unsigned* scratch = (unsigned*)((float*)d_out + (size_t)S_LEN*NTAG - 64);

  k_prep     <<<256,  512, 0, stream>>>(char_emb, char_Wih, char_Whh, char_b, preC, whhTc);
  k_char_lstm<<<512,  256, 0, stream>>>(charsets, char_len, preC, whhTc, embeds);
  k_gather   <<<1024, 256, 0, stream>>>(sentence, word_emb, embeds);
  k_pregate  <<<dim3(128,16,2), 256, 0, stream>>>(embeds, fw_Wih, fw_b, bw_Wih, bw_b, pregates);
  k_recurrent<<<64,   256, 0, stream>>>(fw_Whh, bw_Whh, pregates, hbuf, houtb, scratch);
  k_output   <<<256,  256, 0, stream>>>(houtb, out_W, out_b, out);
}

// Round 2
// 14744.574 us; speedup vs baseline: 2.0524x; 2.0524x over previous
//
#include <hip/hip_runtime.h>

// BiLSTM tagger, MI355X. Round 6: safe skeleton (round-4 poll-wave protocol) +
// unit-aligned mapping (no gacc relay, 1 barrier/step) + guaranteed-resident
// weights (64 floats/thread as named float4s) + probe-verified same-XCD L2
// h-exchange with LLC fallback. Round-5 post-mortem: VGPR=116 proved the
// 240-reg design spilled weights+poll buffers to scratch (3.8us/step); its
// barrier-free chunk-poll was also formally unsafe (nothing gated non-producer
// lanes -> 2-slot overwrite hazard). Both fixed here:
//   - k_recurrent: 64 blocks, active (b&7)<2 so each direction's 8 blocks land
//     on one XCD under round-robin dispatch (heuristic only; probe verifies).
//     576 threads: waves 0-7 compute (thread = 1 unit x 16-k slice, 4 gates),
//     wave 8 polls ALL 256 tagged h slots -> LDS (all-to-all coupling each
//     step => 2-slot alternation provably safe), one __syncthreads per step.
//   - stale-value hazards fixed: k_prep zeroes hbuf and the probe scratch
//     (round 5 relied on stale magics/tags matching across replays).
//   - pregate prefetch depth 3 (HBM ~900cy covered at ~2 steps lead).
//
// Workspace (d_ws) ~92.5 MB (unchanged layout):
//   [0)          preC      256 KB
//   [262144)     whhTc     256 KB
//   [524288)     embeds    12 MB   [8192][384]
//   [13107200)   pregates  64 MB   [2][8192][1024]
//   [80216064)   hout      16 MB   [8192][512]  ([hf|hb])
//   [96993280)   hbuf      8 KB    [2][2][256] u64 tagged h (tag=step+1)
// Probe/verdict scratch: last 256 B of d_out (zeroed by k_prep, overwritten by
// k_output at the end).

#define S_LEN 8192
#define LC    16
#define DW    256
#define DC    64
#define HC    128
#define H2    256
#define NG    1024   // 4*H2
#define NTAG  64
#define CV    128

typedef unsigned long long u64;

__device__ __forceinline__ float sigmoid_f(float x){
  return __frcp_rn(1.0f + __expf(-x));
}
__device__ __forceinline__ float tanh_f(float x){
  float a = fabsf(x);
  float t = 1.0f - 2.0f * __frcp_rn(__expf(2.0f*a) + 1.0f);
  return copysignf(t, x);
}
__device__ __forceinline__ float dot4(float4 w, float4 h){
  return w.x*h.x + w.y*h.y + w.z*h.z + w.w*h.w;
}

// ---------------------------------------------------------------- k_prep
// Also zeroes hbuf (blk 1) and the probe scratch (blk 0) so k_recurrent never
// sees stale tags/magics from a previous launch (kernel-boundary release ->
// acquire makes the zeros visible).
__global__ __launch_bounds__(512) void k_prep(
    const float* __restrict__ char_emb, const float* __restrict__ char_Wih,
    const float* __restrict__ char_Whh, const float* __restrict__ char_b,
    float* __restrict__ preC, float* __restrict__ whhTc,
    u64* __restrict__ hbufz, unsigned* __restrict__ scratchz)
{
  int blk = blockIdx.x, tid = threadIdx.x;
  if (blk == 0 && tid < 64) scratchz[tid] = 0u;
  if (blk == 1){ hbufz[tid] = 0ull; hbufz[tid + 512] = 0ull; }

  __shared__ float esh[DC];
  if (blk < CV){
    if (tid < DC) esh[tid] = char_emb[blk*DC + tid];
    __syncthreads();
    const float* wr = char_Wih + (size_t)tid*DC;
    float acc = char_b[tid];
#pragma unroll
    for (int d=0; d<DC; d+=4){
      float4 wv = *(const float4*)&wr[d];
      acc += wv.x*esh[d] + wv.y*esh[d+1] + wv.z*esh[d+2] + wv.w*esh[d+3];
    }
    preC[(size_t)blk*512 + tid] = acc;
  } else {
    int k = blk - CV;
    whhTc[(size_t)k*512 + tid] = char_Whh[(size_t)tid*HC + k];
  }
}

// ---------------------------------------------------------------- k_char_lstm
__global__ __launch_bounds__(256) void k_char_lstm(
    const int* __restrict__ charsets, const int* __restrict__ lengths,
    const float* __restrict__ preC, const float* __restrict__ whhTc,
    float* __restrict__ embeds)
{
  int blk = blockIdx.x, tid = threadIdx.x;
  int s0 = blk*16;
  __shared__ float h_sh[16][132];
  __shared__ float gsh[512][17];
  __shared__ int   ch_sh[16];

  for (int i = tid; i < 16*132; i += 256) (&h_sh[0][0])[i] = 0.0f;

  int uw  = tid & 15;
  int ujg = tid >> 4;
  float c[8];
#pragma unroll
  for (int u=0; u<8; u++) c[u] = 0.0f;
  int lw = lengths[s0 + uw];

  int g0 = tid, g1 = tid + 256;
  __syncthreads();

  for (int t=0; t<LC; t++){
    if (tid < 16) ch_sh[tid] = charsets[(size_t)(s0+tid)*LC + t];
    __syncthreads();                                        // (A)

    float acc0[16], acc1[16];
#pragma unroll
    for (int w=0; w<16; w++){
      int ch = ch_sh[w];
      acc0[w] = preC[(size_t)ch*512 + g0];
      acc1[w] = preC[(size_t)ch*512 + g1];
    }
    for (int k4=0; k4<HC; k4+=4){
      float w00 = whhTc[(size_t)(k4+0)*512 + g0];
      float w01 = whhTc[(size_t)(k4+1)*512 + g0];
      float w02 = whhTc[(size_t)(k4+2)*512 + g0];
      float w03 = whhTc[(size_t)(k4+3)*512 + g0];
      float w10 = whhTc[(size_t)(k4+0)*512 + g1];
      float w11 = whhTc[(size_t)(k4+1)*512 + g1];
      float w12 = whhTc[(size_t)(k4+2)*512 + g1];
      float w13 = whhTc[(size_t)(k4+3)*512 + g1];
#pragma unroll
      for (int w=0; w<16; w++){
        float4 h4 = *(const float4*)&h_sh[w][k4];
        acc0[w] += w00*h4.x + w01*h4.y + w02*h4.z + w03*h4.w;
        acc1[w] += w10*h4.x + w11*h4.y + w12*h4.z + w13*h4.w;
      }
    }
#pragma unroll
    for (int w=0; w<16; w++){ gsh[g0][w] = acc0[w]; gsh[g1][w] = acc1[w]; }
    __syncthreads();                                        // (G)

    float hnew[8];
#pragma unroll
    for (int u=0; u<8; u++){
      int j = ujg*8 + u;
      float gi = sigmoid_f(gsh[j][uw]);
      float gf = sigmoid_f(gsh[HC + j][uw]);
      float gg = tanh_f   (gsh[2*HC + j][uw]);
      float go = sigmoid_f(gsh[3*HC + j][uw]);
      c[u] = gf*c[u] + gi*gg;
      hnew[u] = go * tanh_f(c[u]);
    }
#pragma unroll
    for (int u=0; u<8; u+=4)
      *(float4*)&h_sh[uw][ujg*8 + u] = make_float4(hnew[u],hnew[u+1],hnew[u+2],hnew[u+3]);
    if (t == lw-1){
#pragma unroll
      for (int u=0; u<8; u+=4)
        *(float4*)&embeds[(size_t)(s0+uw)*384 + ujg*8 + u]
            = make_float4(hnew[u],hnew[u+1],hnew[u+2],hnew[u+3]);
    }
  }
}

// ---------------------------------------------------------------- k_gather
__global__ __launch_bounds__(256) void k_gather(
    const int* __restrict__ sentence, const float* __restrict__ word_emb,
    float* __restrict__ embeds)
{
  int blk = blockIdx.x, tid = threadIdx.x;
  int s = blk*8 + (tid >> 5);
  int lane = tid & 31;
  int idx = sentence[s];
  const float4* src = (const float4*)(word_emb + (size_t)idx*DW);
  float4* dst = (float4*)(embeds + (size_t)s*384 + 128);
  dst[lane]      = src[lane];
  dst[lane + 32] = src[lane + 32];
}

// ---------------------------------------------------------------- k_pregate
// Output layout: pregates[dir][t][n], n = gate-major (PyTorch i,f,g,o blocks of 256)
__global__ __launch_bounds__(256) void k_pregate(
    const float* __restrict__ embeds,
    const float* __restrict__ Wih_fw, const float* __restrict__ b_fw,
    const float* __restrict__ Wih_bw, const float* __restrict__ b_bw,
    float* __restrict__ pregates)
{
  int dir = blockIdx.z;
  const float* W    = dir ? Wih_bw : Wih_fw;
  const float* bias = dir ? b_bw   : b_fw;
  int t0 = blockIdx.x*64, n0 = blockIdx.y*64;
  __shared__ float a_sh[16][68];
  __shared__ float b_sh[16][68];
  int tid = threadIdx.x;
  int li = tid & 63, kq = tid >> 6;
  int ti = tid >> 4, tj = tid & 15;
  float acc[4][4];
#pragma unroll
  for (int ii=0; ii<4; ii++)
#pragma unroll
    for (int jj=0; jj<4; jj++) acc[ii][jj] = 0.0f;

  for (int k0=0; k0<384; k0+=16){
    float4 av = *(const float4*)&embeds[(size_t)(t0+li)*384 + k0 + kq*4];
    float4 bv = *(const float4*)&W     [(size_t)(n0+li)*384 + k0 + kq*4];
    __syncthreads();
    a_sh[kq*4+0][li]=av.x; a_sh[kq*4+1][li]=av.y; a_sh[kq*4+2][li]=av.z; a_sh[kq*4+3][li]=av.w;
    b_sh[kq*4+0][li]=bv.x; b_sh[kq*4+1][li]=bv.y; b_sh[kq*4+2][li]=bv.z; b_sh[kq*4+3][li]=bv.w;
    __syncthreads();
#pragma unroll
    for (int kk=0; kk<16; kk++){
      float4 a4 = *(const float4*)&a_sh[kk][ti*4];
      float4 b4 = *(const float4*)&b_sh[kk][tj*4];
      float aa[4] = {a4.x,a4.y,a4.z,a4.w};
      float bb[4] = {b4.x,b4.y,b4.z,b4.w};
#pragma unroll
      for (int ii=0; ii<4; ii++)
#pragma unroll
        for (int jj=0; jj<4; jj++) acc[ii][jj] += aa[ii]*bb[jj];
    }
  }
  float4 bias4 = *(const float4*)&bias[n0 + tj*4];
  float bb2[4] = {bias4.x,bias4.y,bias4.z,bias4.w};
#pragma unroll
  for (int ii=0; ii<4; ii++){
    float4 o = make_float4(acc[ii][0]+bb2[0], acc[ii][1]+bb2[1],
                           acc[ii][2]+bb2[2], acc[ii][3]+bb2[3]);
    *(float4*)&pregates[((size_t)dir*S_LEN + (t0+ti*4+ii))*NG + n0 + tj*4] = o;
  }
}

// ---------------------------------------------------------------- k_recurrent
// FAST (same-XCD, probe-verified): plain store (write-through L1 -> shared L2),
//   sc0 load (L1 bypass, reads the shared L2).
// LLC  (always-correct fallback): sc0 sc1 both ways = device coherence point.
__device__ __forceinline__ void st_plain_u32(unsigned* p, unsigned v){
  asm volatile("global_store_dword %0, %1, off" :: "v"(p), "v"(v) : "memory");
}
__device__ __forceinline__ unsigned ld_sc0_u32(const unsigned* p){
  unsigned r;
  asm volatile("global_load_dword %0, %1, off sc0\n\t"
               "s_waitcnt vmcnt(0)"
               : "=v"(r) : "v"(p) : "memory");
  return r;
}

// Compute role: thread (r=tid>>4, ke=tid&15); unit = slot*32+r. Holds the 4
// gate rows of its unit x 16-k slice as 16 named float4s (guaranteed VGPR).
// 16-lane shfl_xor all-reduce -> ke==0 lane has all 4 gates -> activation +
// tagged store in-thread. LDS h layout skewed: chunk ke at offset ke*20.
template<bool LLC>
__device__ __forceinline__ void compute_loop(
    int dir, int unit, int ke,
    const float* __restrict__ Whh,
    const float* __restrict__ pgb,
    u64* __restrict__ hb,
    float* __restrict__ hout,
    float* hsh /* [2][320] */)
{
  const float* bp = Whh + (size_t)unit*H2 + ke*16;
  float4 wA0 = *(const float4*)(bp + 0*65536 +  0);
  float4 wA1 = *(const float4*)(bp + 0*65536 +  4);
  float4 wA2 = *(const float4*)(bp + 0*65536 +  8);
  float4 wA3 = *(const float4*)(bp + 0*65536 + 12);
  float4 wB0 = *(const float4*)(bp + 1*65536 +  0);
  float4 wB1 = *(const float4*)(bp + 1*65536 +  4);
  float4 wB2 = *(const float4*)(bp + 1*65536 +  8);
  float4 wB3 = *(const float4*)(bp + 1*65536 + 12);
  float4 wC0 = *(const float4*)(bp + 2*65536 +  0);
  float4 wC1 = *(const float4*)(bp + 2*65536 +  4);
  float4 wC2 = *(const float4*)(bp + 2*65536 +  8);
  float4 wC3 = *(const float4*)(bp + 2*65536 + 12);
  float4 wD0 = *(const float4*)(bp + 3*65536 +  0);
  float4 wD1 = *(const float4*)(bp + 3*65536 +  4);
  float4 wD2 = *(const float4*)(bp + 3*65536 +  8);
  float4 wD3 = *(const float4*)(bp + 3*65536 + 12);

  float c = 0.0f;
  // pregate depth-3 pipeline (ke==0 lanes only; loads pinned by the per-step
  // __syncthreads fences -> ~2 steps of HBM-latency cover).
  float pc0=0,pc1=0,pc2=0,pc3=0, pn0=0,pn1=0,pn2=0,pn3=0, pm0=0,pm1=0,pm2=0,pm3=0;
  if (ke == 0){
    const float* p;
    int t0 = dir ? (S_LEN-1) : 0;
    p = pgb + (size_t)t0*NG + unit; pc0=p[0]; pc1=p[256]; pc2=p[512]; pc3=p[768];
    int t1 = dir ? (S_LEN-2) : 1;
    p = pgb + (size_t)t1*NG + unit; pn0=p[0]; pn1=p[256]; pn2=p[512]; pn3=p[768];
    int t2 = dir ? (S_LEN-3) : 2;
    p = pgb + (size_t)t2*NG + unit; pm0=p[0]; pm1=p[256]; pm2=p[512]; pm3=p[768];
  }

  for (int s=0; s<S_LEN; ++s){
    const float* hr = hsh + (size_t)(s&1)*320 + ke*20;
    float4 h0 = *(const float4*)(hr + 0);
    float4 h1 = *(const float4*)(hr + 4);
    float4 h2 = *(const float4*)(hr + 8);
    float4 h3 = *(const float4*)(hr + 12);
    float a0 = dot4(wA0,h0) + dot4(wA1,h1) + dot4(wA2,h2) + dot4(wA3,h3);
    float a1 = dot4(wB0,h0) + dot4(wB1,h1) + dot4(wB2,h2) + dot4(wB3,h3);
    float a2 = dot4(wC0,h0) + dot4(wC1,h1) + dot4(wC2,h2) + dot4(wC3,h3);
    float a3 = dot4(wD0,h0) + dot4(wD1,h1) + dot4(wD2,h2) + dot4(wD3,h3);
    a0 += __shfl_xor(a0,1); a1 += __shfl_xor(a1,1); a2 += __shfl_xor(a2,1); a3 += __shfl_xor(a3,1);
    a0 += __shfl_xor(a0,2); a1 += __shfl_xor(a1,2); a2 += __shfl_xor(a2,2); a3 += __shfl_xor(a3,2);
    a0 += __shfl_xor(a0,4); a1 += __shfl_xor(a1,4); a2 += __shfl_xor(a2,4); a3 += __shfl_xor(a3,4);
    a0 += __shfl_xor(a0,8); a1 += __shfl_xor(a1,8); a2 += __shfl_xor(a2,8); a3 += __shfl_xor(a3,8);

    if (ke == 0){
      a0 += pc0; a1 += pc1; a2 += pc2; a3 += pc3;
      float gi = sigmoid_f(a0), gf = sigmoid_f(a1), gg = tanh_f(a2), go = sigmoid_f(a3);
      c = gf*c + gi*gg;
      float hn = go * tanh_f(c);
      u64 pack = ((u64)__float_as_uint(hn) << 32) | (u64)(unsigned)(s+1);
      u64* hp = hb + (size_t)((s+1)&1)*H2 + unit;
      if constexpr (LLC)
        asm volatile("global_store_dwordx2 %0, %1, off sc0 sc1" :: "v"(hp), "v"(pack) : "memory");
      else
        asm volatile("global_store_dwordx2 %0, %1, off" :: "v"(hp), "v"(pack) : "memory");
      int t = dir ? (S_LEN-1-s) : s;
      hout[(size_t)t*512 + (size_t)dir*H2 + unit] = hn;
      pc0=pn0; pc1=pn1; pc2=pn2; pc3=pn3;
      pn0=pm0; pn1=pm1; pn2=pm2; pn3=pm3;
      if (s+3 < S_LEN){
        int t3 = dir ? (S_LEN-4-s) : (s+3);
        const float* p3 = pgb + (size_t)t3*NG + unit;
        pm0=p3[0]; pm1=p3[256]; pm2=p3[512]; pm3=p3[768];
      }
    }
    __syncthreads();
  }
}

// Poll role (wave 8, 64 lanes): polls ALL 256 tagged slots (4 per lane) of the
// step's hbuf slot, writes h into the skewed LDS buffer. Polling all units
// gives the all-to-all step coupling that makes 2-slot alternation safe.
template<bool LLC>
__device__ __forceinline__ void poll_loop(
    int lane, u64* __restrict__ hb, float* hsh)
{
  for (int s=0; s<S_LEN; ++s){
    if (s+1 < S_LEN){
      unsigned tag = (unsigned)(s+1);
      const u64* pp = hb + (size_t)((s+1)&1)*H2 + lane;
      u64 v0,v1,v2,v3;
      for (;;){
        if constexpr (LLC)
          asm volatile(
            "global_load_dwordx2 %0, %4, off sc0 sc1\n\t"
            "global_load_dwordx2 %1, %4, off offset:512 sc0 sc1\n\t"
            "global_load_dwordx2 %2, %4, off offset:1024 sc0 sc1\n\t"
            "global_load_dwordx2 %3, %4, off offset:1536 sc0 sc1\n\t"
            "s_waitcnt vmcnt(0)"
            : "=&v"(v0),"=&v"(v1),"=&v"(v2),"=&v"(v3) : "v"(pp) : "memory");
        else
          asm volatile(
            "global_load_dwordx2 %0, %4, off sc0\n\t"
            "global_load_dwordx2 %1, %4, off offset:512 sc0\n\t"
            "global_load_dwordx2 %2, %4, off offset:1024 sc0\n\t"
            "global_load_dwordx2 %3, %4, off offset:1536 sc0\n\t"
            "s_waitcnt vmcnt(0)"
            : "=&v"(v0),"=&v"(v1),"=&v"(v2),"=&v"(v3) : "v"(pp) : "memory");
        if ( ((unsigned)v0==tag) & ((unsigned)v1==tag) &
             ((unsigned)v2==tag) & ((unsigned)v3==tag) ) break;
      }
      float* hd = hsh + (size_t)((s+1)&1)*320;
      int klo = lane & 15;
      hd[((lane      )>>4)*20 + klo] = __uint_as_float((unsigned)(v0>>32));
      hd[((lane +  64)>>4)*20 + klo] = __uint_as_float((unsigned)(v1>>32));
      hd[((lane + 128)>>4)*20 + klo] = __uint_as_float((unsigned)(v2>>32));
      hd[((lane + 192)>>4)*20 + klo] = __uint_as_float((unsigned)(v3>>32));
    }
    __syncthreads();
  }
}

__global__ __launch_bounds__(576, 1) void k_recurrent(
    const float* __restrict__ Whh_fw, const float* __restrict__ Whh_bw,
    const float* __restrict__ pregates,
    u64* __restrict__ hbuf,
    float* __restrict__ hout,
    unsigned* __restrict__ scratch)
{
  int b = blockIdx.x;
  if ((b & 7) > 1) return;
  const int dir  = b & 7;          // 0 or 1
  const int slot = b >> 3;         // 0..7
  const int tid  = threadIdx.x;

  __shared__ float hsh[2*320];     // skewed: unit u at (u>>4)*20 + (u&15)
  __shared__ int fast_sh;
  for (int i=tid; i<2*320; i+=576) hsh[i] = 0.0f;

  // ---- functional same-XCD probe (bounded; any failure -> LLC fallback).
  // Scratch is zeroed by k_prep each launch, so no stale-magic false
  // positives and no mixed verdicts (f1/f2 are ANDs of identical data).
  if (tid == 0){
    unsigned* probe = scratch;        // [16]
    unsigned* verd1 = scratch + 16;   // [16]
    unsigned* verd2 = scratch + 32;   // [16]
    st_plain_u32(&probe[dir*8 + slot], 0xA5C70000u | (unsigned)slot);
    unsigned have = 0;
    for (int it = 0; it < 400 && have != 0xFFu; ++it)
      for (int i = 0; i < 8; ++i)
        if (!((have >> i) & 1u) &&
            ld_sc0_u32(&probe[dir*8 + i]) == (0xA5C70000u | (unsigned)i))
          have |= 1u << i;
    unsigned ok = (have == 0xFFu) ? 1u : 0u;
    __hip_atomic_store(&verd1[dir*8 + slot], 0x5EED0000u | ok,
                       __ATOMIC_RELAXED, __HIP_MEMORY_SCOPE_AGENT);
    unsigned f1 = 1;
    for (int i = 0; i < 8; ++i){
      unsigned v;
      do v = __hip_atomic_load(&verd1[dir*8 + i], __ATOMIC_RELAXED, __HIP_MEMORY_SCOPE_AGENT);
      while ((v & 0xFFFF0000u) != 0x5EED0000u);
      f1 &= v & 1u;
    }
    unsigned f2 = 0;
    if (f1){   // f1 identical across blocks (AND of same data) -> no hang
      st_plain_u32(&probe[dir*8 + slot], 0x0DDB0000u | (unsigned)slot);
      have = 0;
      for (int it = 0; it < 400 && have != 0xFFu; ++it)
        for (int i = 0; i < 8; ++i)
          if (!((have >> i) & 1u) &&
              ld_sc0_u32(&probe[dir*8 + i]) == (0x0DDB0000u | (unsigned)i))
            have |= 1u << i;
      ok = (have == 0xFFu) ? 1u : 0u;
      __hip_atomic_store(&verd2[dir*8 + slot], 0x7EED0000u | ok,
                         __ATOMIC_RELAXED, __HIP_MEMORY_SCOPE_AGENT);
      f2 = 1;
      for (int i = 0; i < 8; ++i){
        unsigned v;
        do v = __hip_atomic_load(&verd2[dir*8 + i], __ATOMIC_RELAXED, __HIP_MEMORY_SCOPE_AGENT);
        while ((v & 0xFFFF0000u) != 0x7EED0000u);
        f2 &= v & 1u;
      }
    }
    fast_sh = (int)(f1 & f2);
  }
  __syncthreads();
  const bool fast = (fast_sh != 0);

  const float* Whh = dir ? Whh_bw : Whh_fw;
  const float* pgb = pregates + (size_t)dir * S_LEN * NG;
  u64* hb = hbuf + (size_t)dir * 2 * H2;

  if (tid < 512){
    int r = tid >> 4, ke = tid & 15;
    int unit = slot*32 + r;
    if (fast) compute_loop<false>(dir, unit, ke, Whh, pgb, hb, hout, hsh);
    else      compute_loop<true >(dir, unit, ke, Whh, pgb, hb, hout, hsh);
  } else {
    int lane = tid - 512;
    if (fast) poll_loop<false>(lane, hb, hsh);
    else      poll_loop<true >(lane, hb, hsh);
  }
}

// ---------------------------------------------------------------- k_output
__global__ __launch_bounds__(256) void k_output(
    const float* __restrict__ hout, const float* __restrict__ outW,
    const float* __restrict__ outb, float* __restrict__ out)
{
  __shared__ float wT[128][66];
  __shared__ float hsh[32][132];
  __shared__ float lsh[32][66];
  __shared__ float msh[32][2];
  int t0 = blockIdx.x*32, tid = threadIdx.x;
  int n  = tid & 63, tg = tid >> 6;
  int sl = tid >> 3, kg = tid & 7;
  int wn = tid & 63, wk = tid >> 6;
  float acc[8];
#pragma unroll
  for (int u=0; u<8; u++) acc[u] = 0.0f;

  for (int kc=0; kc<4; kc++){
    int k0 = kc*128;
    float4 wreg[8];
#pragma unroll
    for (int e=0; e<8; e++) wreg[e] = *(const float4*)&outW[(size_t)wn*512 + k0 + wk*32 + e*4];
    float4 hreg[4];
#pragma unroll
    for (int e=0; e<4; e++) hreg[e] = *(const float4*)&hout[(size_t)(t0+sl)*512 + k0 + kg*16 + e*4];
    __syncthreads();
#pragma unroll
    for (int e=0; e<8; e++){
      int kk = wk*32 + e*4;
      wT[kk+0][wn]=wreg[e].x; wT[kk+1][wn]=wreg[e].y; wT[kk+2][wn]=wreg[e].z; wT[kk+3][wn]=wreg[e].w;
    }
#pragma unroll
    for (int e=0; e<4; e++) *(float4*)&hsh[sl][kg*16 + e*4] = hreg[e];
    __syncthreads();
#pragma unroll
    for (int kk4=0; kk4<128; kk4+=4){
      float w0 = wT[kk4+0][n], w1 = wT[kk4+1][n], w2 = wT[kk4+2][n], w3 = wT[kk4+3][n];
#pragma unroll
      for (int u=0; u<8; u++){
        float4 h4 = *(const float4*)&hsh[tg*8+u][kk4];
        acc[u] += w0*h4.x + w1*h4.y + w2*h4.z + w3*h4.w;
      }
    }
  }
  float bn = outb[n];
#pragma unroll
  for (int u=0; u<8; u++) lsh[tg*8+u][n] = acc[u] + bn;
  __syncthreads();
  if (tid < 32){
    float M = -3.4e38f;
    for (int j=0; j<NTAG; j++) M = fmaxf(M, lsh[tid][j]);
    float ssum = 0.0f;
    for (int j=0; j<NTAG; j++) ssum += expf(lsh[tid][j] - M);
    msh[tid][0] = M; msh[tid][1] = logf(ssum);
  }
  __syncthreads();
#pragma unroll
  for (int u=0; u<8; u++){
    int tt = tg*8+u;
    out[(size_t)(t0+tt)*NTAG + n] = lsh[tt][n] - msh[tt][0] - msh[tt][1];
  }
}

// ---------------------------------------------------------------- launch
extern "C" void kernel_launch(void* const* d_in, const int* in_sizes, int n_in,
                              void* d_out, int out_size, void* d_ws, size_t ws_size,
                              hipStream_t stream)
{
  (void)in_sizes; (void)n_in; (void)out_size; (void)ws_size;
  const int*   sentence = (const int*)d_in[0];
  const int*   charsets = (const int*)d_in[1];
  const int*   char_len = (const int*)d_in[2];
  const float* word_emb = (const float*)d_in[3];
  const float* char_emb = (const float*)d_in[4];
  const float* char_Wih = (const float*)d_in[5];
  const float* char_Whh = (const float*)d_in[6];
  const float* char_b   = (const float*)d_in[7];
  const float* fw_Wih   = (const float*)d_in[8];
  const float* fw_Whh   = (const float*)d_in[9];
  const float* fw_b     = (const float*)d_in[10];
  const float* bw_Wih   = (const float*)d_in[11];
  const float* bw_Whh   = (const float*)d_in[12];
  const float* bw_b     = (const float*)d_in[13];
  const float* out_W    = (const float*)d_in[14];
  const float* out_b    = (const float*)d_in[15];
  float* out = (float*)d_out;

  char* ws = (char*)d_ws;
  float* preC     = (float*)(ws);
  float* whhTc    = (float*)(ws + 262144);
  float* embeds   = (float*)(ws + 524288);
  float* pregates = (float*)(ws + 13107200);
  float* houtb    = (float*)(ws + 80216064);
  u64*   hbuf     = (u64*)(ws + 96993280);
  // probe/verdict scratch: last 256 B of d_out (zeroed by k_prep, overwritten
  // by k_output later).
  unsigned* scratch = (unsigned*)((float*)d_out + (size_t)S_LEN*NTAG - 64);

  k_prep     <<<256,  512, 0, stream>>>(char_emb, char_Wih, char_Whh, char_b,
                                        preC, whhTc, hbuf, scratch);
  k_char_lstm<<<512,  256, 0, stream>>>(charsets, char_len, preC, whhTc, embeds);
  k_gather   <<<1024, 256, 0, stream>>>(sentence, word_emb, embeds);
  k_pregate  <<<dim3(128,16,2), 256, 0, stream>>>(embeds, fw_Wih, fw_b, bw_Wih, bw_b, pregates);
  k_recurrent<<<64,   576, 0, stream>>>(fw_Whh, bw_Whh, pregates, hbuf, houtb, scratch);
  k_output   <<<256,  256, 0, stream>>>(houtb, out_W, out_b, out);
}